// Round 6
// baseline (1706.421 us; speedup 1.0000x reference)
//
#include <hip/hip_runtime.h>
#include <cstdint>
#include <cstddef>

#define N_NODES_C 262144
#define N_EDGES_C 524288
#define N_GRAPHS_C 8192
#define BN_EPS_C 1e-5f

typedef short short8 __attribute__((ext_vector_type(8)));
typedef float f32x4 __attribute__((ext_vector_type(4)));

union Frag { int2 p2[2]; short8 v8; };

__device__ __forceinline__ unsigned short f2bf(float f) {
  unsigned int u = __float_as_uint(f);
  u += 0x7fffu + ((u >> 16) & 1u);   // RN-even
  return (unsigned short)(u >> 16);
}
__device__ __forceinline__ float bf2f(unsigned short h) {
  return __uint_as_float(((unsigned int)h) << 16);
}

// ================================================================ CSR build (once per launch)
__global__ __launch_bounds__(256) void hist_kernel(const int* __restrict__ dst, int* __restrict__ cnt) {
  int e = blockIdx.x * 256 + threadIdx.x;
  if (e < N_EDGES_C) atomicAdd(&cnt[dst[e]], 1);
}

__global__ __launch_bounds__(256) void scanA_kernel(const int* __restrict__ cnt,
                                                    int* __restrict__ rs, int* __restrict__ bsums) {
  __shared__ int lds[256];
  const int b = blockIdx.x, t = threadIdx.x;
  int4 v = ((const int4*)(cnt + b * 1024))[t];
  lds[t] = v.x + v.y + v.z + v.w;
  __syncthreads();
  for (int off = 1; off < 256; off <<= 1) {
    int add = (t >= off) ? lds[t - off] : 0;
    __syncthreads();
    lds[t] += add;
    __syncthreads();
  }
  int excl = (t > 0) ? lds[t - 1] : 0;
  if (t == 255) bsums[b] = lds[255];
  int4 o;
  o.x = excl; o.y = excl + v.x; o.z = excl + v.x + v.y; o.w = excl + v.x + v.y + v.z;
  ((int4*)(rs + b * 1024))[t] = o;
}

__global__ __launch_bounds__(256) void scanB_kernel(int* __restrict__ bsums) {
  __shared__ int lds[256];
  const int t = threadIdx.x;
  lds[t] = bsums[t];
  __syncthreads();
  for (int off = 1; off < 256; off <<= 1) {
    int add = (t >= off) ? lds[t - off] : 0;
    __syncthreads();
    lds[t] += add;
    __syncthreads();
  }
  bsums[t] = (t > 0) ? lds[t - 1] : 0;
}

__global__ __launch_bounds__(256) void scanC_kernel(int* __restrict__ rs, int* __restrict__ cursor,
                                                    const int* __restrict__ bsums) {
  int i = blockIdx.x * 256 + threadIdx.x;
  int v = rs[i] + bsums[i >> 10];
  rs[i] = v;
  cursor[i] = v;
  if (i == 0) rs[N_NODES_C] = N_EDGES_C;
}

__global__ __launch_bounds__(256) void edge_bucket_kernel(const int* __restrict__ src,
                                                          const int* __restrict__ dst,
                                                          int* __restrict__ cursor,
                                                          int* __restrict__ ebuf) {
  int e = blockIdx.x * 256 + threadIdx.x;
  if (e >= N_EDGES_C) return;
  int pos = atomicAdd(&cursor[dst[e]], 1);
  ebuf[pos] = src[e];
}

// ================================================================ layer-0 gather: x[N,77] -> padded agg[N,128]
__global__ __launch_bounds__(256) void agg77_kernel(const float* __restrict__ x,
                                                    const int* __restrict__ rs,
                                                    const int* __restrict__ ebuf,
                                                    float* __restrict__ agg) {
  int idx = blockIdx.x * 256 + threadIdx.x;
  int n = idx >> 5, q = idx & 31;
  int s = rs[n], e = rs[n + 1];
  const size_t nb = (size_t)n * 77;
  float v0 = x[nb + q];
  float v1 = x[nb + q + 32];
  float v2 = (q < 13) ? x[nb + q + 64] : 0.f;
  for (int i = s; i < e; ++i) {
    const size_t sb = (size_t)ebuf[i] * 77;
    v0 += x[sb + q];
    v1 += x[sb + q + 32];
    if (q < 13) v2 += x[sb + q + 64];
  }
  const size_t ob = (size_t)n * 128;
  agg[ob + q] = v0;
  agg[ob + q + 32] = v1;
  agg[ob + q + 64] = (q < 13) ? v2 : 0.f;
  agg[ob + q + 96] = 0.f;
}

// ================================================================ weight split + frag-pack (once)
// Per matrix (128x128, w0a zero-padded past k=77): 32768 shorts = 4 p-slices of 8192:
//   p0 = hi j0..3, p1 = hi j4..7, p2 = lo j0..3, p3 = lo j4..7
// each p-slice: [frag f=ct*4+ks (32)][lane (64)][4 shorts]  (8 B/lane -> ds_read_b64, 2-way free)
// frag element: W[k = ks*32 + (lane>>4)*8 + j][c = ct*16 + (lane&15)]
__global__ __launch_bounds__(256) void wsplit_kernel(const float* __restrict__ w0a,
                                                     const float* __restrict__ w0b,
                                                     const float* __restrict__ wa,
                                                     const float* __restrict__ wb,
                                                     unsigned short* __restrict__ Wpk) {
  int tid = blockIdx.x * 256 + threadIdx.x;  // 20480 = 10 mats x 32 frags x 64 lanes
  int m = tid >> 11;
  int rem = tid & 2047;
  int f = rem >> 6;          // ct*4+ks
  int l = rem & 63;
  int ct = f >> 2, ks = f & 3;
  int c = ct * 16 + (l & 15);
  const size_t mb = (size_t)m * 32768;
  const size_t fl = (size_t)(f * 64 + l) * 4;
#pragma unroll
  for (int j = 0; j < 8; ++j) {
    int k = ks * 32 + ((l >> 4) << 3) + j;
    float w;
    if (m == 0)      w = (k < 77) ? w0a[k * 128 + c] : 0.f;
    else if (m == 1) w = w0b[k * 128 + c];
    else if (m < 6)  w = wa[(size_t)(m - 2) * 16384 + k * 128 + c];
    else             w = wb[(size_t)(m - 6) * 16384 + k * 128 + c];
    unsigned short hh = f2bf(w);
    unsigned short ll = f2bf(w - bf2f(hh));
    if (j < 4) {
      Wpk[mb + fl + j] = hh;
      Wpk[mb + 16384 + fl + j] = ll;
    } else {
      Wpk[mb + 8192 + fl + (j - 4)] = hh;
      Wpk[mb + 24576 + fl + (j - 4)] = ll;
    }
  }
}

// ================================================================ fused layer: gather(+BN) -> MLP (2 GEMMs) -> raw H + stats
// 512 thr = 8 waves; grid 256 (1 block/CU). Block owns 1024 rows = 8 strips of 128.
// LDS: sW2 64 KB persistent; sW1C 64 KB = W1 (restaged per strip) then C1 (XOR-swizzled).
template <bool GATHER>
__global__ __launch_bounds__(512, 2) void fused_layer_kernel(
    const float* __restrict__ Hin,      // raw prev-layer h (or padded AGG for layer 0)
    const int* __restrict__ rs,
    const int* __restrict__ ebuf,
    const float* __restrict__ Sprev,    // stats of Hin (GATHER only)
    const float* __restrict__ gprev,    // gamma slice of prev layer (GATHER only)
    const float* __restrict__ bprev,    // beta slice (GATHER only)
    const unsigned short* __restrict__ W1pk,
    const unsigned short* __restrict__ W2pk,
    const float* __restrict__ b1,
    const float* __restrict__ b2,
    float* __restrict__ Hout,
    float* __restrict__ Sout) {
  __shared__ int4 sW2[4096];    // 64 KB
  __shared__ int4 sW1C[4096];   // 64 KB
  __shared__ float bsum[128];
  __shared__ float bsq[128];

  const int t = threadIdx.x;
  const int lane = t & 63;
  const int wv = t >> 6;      // 0..7
  const int cb = lane & 15;
  const int g = lane >> 4;    // 0..3

  // stage W2 once (synced by first strip's bar1)
  {
    const int4* s2 = (const int4*)W2pk;
#pragma unroll
    for (int i = 0; i < 8; ++i) sW2[t + i * 512] = s2[t + i * 512];
  }

  float bc1[8], bc2[8];
#pragma unroll
  for (int ct = 0; ct < 8; ++ct) {
    bc1[ct] = b1[ct * 16 + cb];
    bc2[ct] = b2[ct * 16 + cb];
  }

  // BN affine coeffs for this lane's gather features: f(q,j) = (q>>1)*32 + g*8 + (q&1)*4 + j
  f32x4 scv[8], shv[8];
  if constexpr (GATHER) {
    const float inv_n = 1.0f / (float)N_NODES_C;
#pragma unroll
    for (int q = 0; q < 8; ++q) {
      int f0 = (q >> 1) * 32 + g * 8 + (q & 1) * 4;
#pragma unroll
      for (int j = 0; j < 4; ++j) {
        int f = f0 + j;
        float mean = Sprev[f] * inv_n;
        float var = Sprev[128 + f] * inv_n - mean * mean;
        float sc = gprev[f] * rsqrtf(var + BN_EPS_C);
        scv[q][j] = sc;
        shv[q][j] = bprev[f] - mean * sc;
      }
    }
  }

  float ssum[8] = {}, ssq[8] = {};
  const size_t blockRow0 = (size_t)blockIdx.x * 1024;

  for (int it = 0; it < 8; ++it) {
    const size_t strip = blockRow0 + it * 128;
    const size_t wrow0 = strip + wv * 16;

    __syncthreads();  // prior iteration's C1 reads done
    // ---- stage W1 into sW1C
    {
      const int4* s1 = (const int4*)W1pk;
#pragma unroll
      for (int i = 0; i < 8; ++i) sW1C[t + i * 512] = s1[t + i * 512];
    }

    // ---- gather + BN (registers only; overlaps staging)
    f32x4 va[8];
    {
      const size_t r = wrow0 + cb;
      const float* hp = Hin + r * 128 + g * 8;
#pragma unroll
      for (int q = 0; q < 8; ++q)
        va[q] = *(const f32x4*)(hp + (q >> 1) * 32 + (q & 1) * 4);
      if constexpr (GATHER) {
        int s = rs[r], e = rs[r + 1];
        for (int i = s; i < e; ++i) {
          const float* hq = Hin + (size_t)ebuf[i] * 128 + g * 8;
#pragma unroll
          for (int q = 0; q < 8; ++q)
            va[q] += *(const f32x4*)(hq + (q >> 1) * 32 + (q & 1) * 4);
        }
        float cnt = (float)(e - s + 1);
#pragma unroll
        for (int q = 0; q < 8; ++q) va[q] = va[q] * scv[q] + cnt * shv[q];
      }
    }

    // split A into bf16 hi/lo frags per ks
    Frag ah[4], al[4];
#pragma unroll
    for (int ks = 0; ks < 4; ++ks) {
#pragma unroll
      for (int j = 0; j < 8; ++j) {
        float fv = va[ks * 2 + (j >> 2)][j & 3];
        unsigned short hh = f2bf(fv);
        ah[ks].v8[j] = (short)hh;
        al[ks].v8[j] = (short)f2bf(fv - bf2f(hh));
      }
    }

    __syncthreads();  // W1 staged

    // ---- GEMM1
    f32x4 d1[8] = {};
    {
      const int2* R1 = (const int2*)sW1C;
#pragma unroll
      for (int ks = 0; ks < 4; ++ks) {
#pragma unroll
        for (int ct = 0; ct < 8; ++ct) {
          int fi = (ct * 4 + ks) * 64 + lane;
          Frag wh, wl;
          wh.p2[0] = R1[fi];        wh.p2[1] = R1[2048 + fi];
          wl.p2[0] = R1[4096 + fi]; wl.p2[1] = R1[6144 + fi];
          d1[ct] = __builtin_amdgcn_mfma_f32_16x16x32_bf16(ah[ks].v8, wh.v8, d1[ct], 0, 0, 0);
          d1[ct] = __builtin_amdgcn_mfma_f32_16x16x32_bf16(al[ks].v8, wh.v8, d1[ct], 0, 0, 0);
          d1[ct] = __builtin_amdgcn_mfma_f32_16x16x32_bf16(ah[ks].v8, wl.v8, d1[ct], 0, 0, 0);
        }
      }
    }
    __syncthreads();  // done reading W1

    // ---- C1 = relu(d1 + b1) -> LDS (XOR-swizzled rows), overwrites W1 region
    {
      char* c1b = (char*)sW1C;
#pragma unroll
      for (int ct = 0; ct < 8; ++ct) {
#pragma unroll
        for (int j = 0; j < 4; ++j) {
          int r = wv * 16 + g * 4 + j;
          int c = ct * 16 + cb;
          float v = fmaxf(d1[ct][j] + bc1[ct], 0.f);
          *(float*)(c1b + ((r * 512 + c * 4) ^ ((r & 7) << 4))) = v;
        }
      }
    }
    __syncthreads();  // C1 complete

    // ---- GEMM2 (A = C1 from LDS, B = sW2)
    f32x4 d2[8] = {};
    {
      const int rr = wv * 16 + cb;
      const char* c1r = (const char*)sW1C;
      const int2* R2 = (const int2*)sW2;
#pragma unroll
      for (int ks = 0; ks < 4; ++ks) {
        int base = rr * 512 + ks * 128 + g * 32;
        f32x4 x0 = *(const f32x4*)(c1r + ((base) ^ ((rr & 7) << 4)));
        f32x4 x1 = *(const f32x4*)(c1r + ((base + 16) ^ ((rr & 7) << 4)));
        Frag a2h, a2l;
#pragma unroll
        for (int j = 0; j < 8; ++j) {
          float fv = (j < 4) ? x0[j] : x1[j - 4];
          unsigned short hh = f2bf(fv);
          a2h.v8[j] = (short)hh;
          a2l.v8[j] = (short)f2bf(fv - bf2f(hh));
        }
#pragma unroll
        for (int ct = 0; ct < 8; ++ct) {
          int fi = (ct * 4 + ks) * 64 + lane;
          Frag wh, wl;
          wh.p2[0] = R2[fi];        wh.p2[1] = R2[2048 + fi];
          wl.p2[0] = R2[4096 + fi]; wl.p2[1] = R2[6144 + fi];
          d2[ct] = __builtin_amdgcn_mfma_f32_16x16x32_bf16(a2h.v8, wh.v8, d2[ct], 0, 0, 0);
          d2[ct] = __builtin_amdgcn_mfma_f32_16x16x32_bf16(a2l.v8, wh.v8, d2[ct], 0, 0, 0);
          d2[ct] = __builtin_amdgcn_mfma_f32_16x16x32_bf16(a2h.v8, wl.v8, d2[ct], 0, 0, 0);
        }
      }
    }

    // ---- epilogue: raw H2 store + stats partials
#pragma unroll
    for (int ct = 0; ct < 8; ++ct) {
      const int c = ct * 16 + cb;
#pragma unroll
      for (int j = 0; j < 4; ++j) {
        size_t r = wrow0 + g * 4 + j;
        float v = fmaxf(d2[ct][j] + bc2[ct], 0.f);
        Hout[r * 128 + c] = v;
        ssum[ct] += v;
        ssq[ct] += v * v;
      }
    }
  }

  // ---- stats reduce
  if (t < 128) { bsum[t] = 0.f; bsq[t] = 0.f; }
  __syncthreads();
#pragma unroll
  for (int ct = 0; ct < 8; ++ct) {
    atomicAdd(&bsum[ct * 16 + cb], ssum[ct]);
    atomicAdd(&bsq[ct * 16 + cb], ssq[ct]);
  }
  __syncthreads();
  if (t < 128) {
    atomicAdd(&Sout[t], bsum[t]);
    atomicAdd(&Sout[128 + t], bsq[t]);
  }
}

// ================================================================ pool: normalized segment_max (read-only)
__global__ __launch_bounds__(256) void pool_kernel(const float* __restrict__ h,
                                                   const float* __restrict__ stats,
                                                   const float* __restrict__ gamma,
                                                   const float* __restrict__ beta,
                                                   float* __restrict__ out, int layer) {
  __shared__ float red[256];
  const int gph = blockIdx.x;
  const int t = threadIdx.x;
  const int f = t & 127, half = t >> 7;

  const float inv_n = 1.0f / (float)N_NODES_C;
  float mean = stats[f] * inv_n;
  float var = stats[128 + f] * inv_n - mean * mean;
  float sc = gamma[f] * rsqrtf(var + BN_EPS_C);
  float sh = beta[f] - mean * sc;

  float m = -3.4e38f;
  size_t base = ((size_t)gph * 32 + half * 16) * 128 + f;
#pragma unroll
  for (int r = 0; r < 16; ++r)
    m = fmaxf(m, h[base + (size_t)r * 128] * sc + sh);
  red[t] = m;
  __syncthreads();
  if (t < 128) out[(size_t)gph * 640 + layer * 128 + f] = fmaxf(red[t], red[t + 128]);
}

// ================================================================ launch
extern "C" void kernel_launch(void* const* d_in, const int* in_sizes, int n_in,
                              void* d_out, int out_size, void* d_ws, size_t ws_size,
                              hipStream_t stream) {
  const float* x = (const float*)d_in[0];
  const int* ei = (const int*)d_in[1];
  const int* src = ei;
  const int* dst = ei + N_EDGES_C;
  const float* w0a = (const float*)d_in[3];
  const float* b0a = (const float*)d_in[4];
  const float* w0b = (const float*)d_in[5];
  const float* b0b = (const float*)d_in[6];
  const float* wa = (const float*)d_in[7];
  const float* ba = (const float*)d_in[8];
  const float* wb = (const float*)d_in[9];
  const float* bb = (const float*)d_in[10];
  const float* gamma = (const float*)d_in[11];
  const float* beta = (const float*)d_in[12];
  float* out = (float*)d_out;

  const size_t NNf = (size_t)N_NODES_C * 128;
  float* ws = (float*)d_ws;
  float* Hb0 = ws;
  float* Hb1 = ws + NNf;                 // also serves as padded AGG for layer 0
  float* STATS = ws + 2 * NNf;           // 5 x 256
  int* cnt = (int*)(STATS + 5 * 256);
  int* rowstart = cnt + N_NODES_C;       // N_NODES+1 used
  int* cursor = rowstart + N_NODES_C + 4;
  int* bsums = cursor + N_NODES_C;
  int* ebuf = bsums + 256;
  unsigned short* Wpk = (unsigned short*)(((uintptr_t)(ebuf + N_EDGES_C) + 63) & ~(uintptr_t)63);

  // ---------- prep: weight pack + CSR + stats zero
  wsplit_kernel<<<80, 256, 0, stream>>>(w0a, w0b, wa, wb, Wpk);
  hipMemsetAsync(cnt, 0, N_NODES_C * sizeof(int), stream);
  hipMemsetAsync(STATS, 0, 5 * 256 * sizeof(float), stream);
  hist_kernel<<<N_EDGES_C / 256, 256, 0, stream>>>(dst, cnt);
  scanA_kernel<<<256, 256, 0, stream>>>(cnt, rowstart, bsums);
  scanB_kernel<<<1, 256, 0, stream>>>(bsums);
  scanC_kernel<<<N_NODES_C / 256, 256, 0, stream>>>(rowstart, cursor, bsums);
  edge_bucket_kernel<<<N_EDGES_C / 256, 256, 0, stream>>>(src, dst, cursor, ebuf);

  // ---------- layer 0: gather x -> AGG(Hb1), fused MLP (no BN on input)
  agg77_kernel<<<(N_NODES_C * 32) / 256, 256, 0, stream>>>(x, rowstart, ebuf, Hb1);
  fused_layer_kernel<false><<<256, 512, 0, stream>>>(
      Hb1, rowstart, ebuf, nullptr, nullptr, nullptr,
      Wpk + 0 * 32768, Wpk + 1 * 32768, b0a, b0b, Hb0, STATS + 0 * 256);
  pool_kernel<<<N_GRAPHS_C, 256, 0, stream>>>(Hb0, STATS + 0 * 256, gamma, beta, out, 0);

  // ---------- layers 1..4
  float* cur = Hb0;
  float* nxt = Hb1;
  for (int i = 1; i < 5; ++i) {
    fused_layer_kernel<true><<<256, 512, 0, stream>>>(
        cur, rowstart, ebuf,
        STATS + (size_t)(i - 1) * 256, gamma + (size_t)(i - 1) * 128, beta + (size_t)(i - 1) * 128,
        Wpk + (size_t)(2 + (i - 1)) * 32768, Wpk + (size_t)(6 + (i - 1)) * 32768,
        ba + (size_t)(i - 1) * 128, bb + (size_t)(i - 1) * 128,
        nxt, STATS + (size_t)i * 256);
    pool_kernel<<<N_GRAPHS_C, 256, 0, stream>>>(nxt, STATS + (size_t)i * 256,
                                                gamma + (size_t)i * 128, beta + (size_t)i * 128,
                                                out, i);
    float* tmp = cur; cur = nxt; nxt = tmp;
  }
}